// Round 2
// 531.935 us; speedup vs baseline: 1.0085x; 1.0085x over previous
//
#include <hip/hip_runtime.h>
#include <stdint.h>

// Problem dims
#define B_  32
#define T_  512
#define DE_ 512
#define H_  640
#define V_  4096
#define J_  640

typedef __attribute__((ext_vector_type(4))) float  f32x4;
typedef __attribute__((ext_vector_type(8))) __bf16 bf16x8;

typedef __attribute__((address_space(3))) void LdsV;
typedef __attribute__((address_space(1))) void GloV;

__device__ __forceinline__ unsigned short f2bf(float f) {
    uint32_t u = __builtin_bit_cast(uint32_t, f);
    u += 0x7fffu + ((u >> 16) & 1u);   // round-to-nearest-even
    return (unsigned short)(u >> 16);
}

// compiler+hw fences (memory clobber: hipcc may hoist LDS ops past bare builtins)
__device__ __forceinline__ void sbar() { asm volatile("s_barrier" ::: "memory"); }

// ---------------- fp32 -> bf16 elementwise convert ----------------
__global__ void conv_f32_bf16_k(const float* __restrict__ src,
                                unsigned short* __restrict__ dst, int n) {
    int i = blockIdx.x * blockDim.x + threadIdx.x;
    if (i < n) dst[i] = f2bf(src[i]);
}

// ---------------- encoder (B,D,T) -> bf16 (B*T, D) transpose ----------------
__global__ void enc_transpose_k(const float* __restrict__ enc,
                                unsigned short* __restrict__ out) {
    __shared__ float tile[32][33];
    int b  = blockIdx.z;
    int t0 = blockIdx.x * 32, d0 = blockIdx.y * 32;
    int tx = threadIdx.x & 31;
    int ty = (threadIdx.x >> 5) * 4;
    const float* src = enc + ((size_t)b * DE_ + d0) * T_ + t0;
#pragma unroll
    for (int i = 0; i < 4; i++)
        tile[ty + i][tx] = src[(size_t)(ty + i) * T_ + tx];  // coalesced over t
    __syncthreads();
    unsigned short* dst = out + ((size_t)b * T_ + t0) * DE_ + d0;
#pragma unroll
    for (int i = 0; i < 4; i++)
        dst[(size_t)(ty + i) * DE_ + tx] = f2bf(tile[tx][ty + i]);  // coalesced over d
}

// ---------------- LSTM gates: gates[b][n] = x_b . wih[n] + h_b . whh[n] + biases ----------------
__global__ void lstm_gates_k(const float* __restrict__ x, const int* __restrict__ tok,
                             const float* __restrict__ emb, const float* __restrict__ h,
                             const float* __restrict__ wih, const float* __restrict__ whh,
                             const float* __restrict__ bih, const float* __restrict__ bhh,
                             float* __restrict__ gates) {
    int n = blockIdx.x, lane = threadIdx.x;
    float wi[10], wh[10];
#pragma unroll
    for (int i = 0; i < 10; i++) {
        wi[i] = wih[(size_t)n * H_ + lane + 64 * i];   // coalesced
        wh[i] = whh[(size_t)n * H_ + lane + 64 * i];
    }
    float bias = bih[n] + bhh[n];
    for (int b = 0; b < B_; b++) {
        const float* xr = tok ? (emb + (size_t)tok[b] * H_) : (x + (size_t)b * H_);
        const float* hr = h + (size_t)b * H_;
        float s = 0.f;
#pragma unroll
        for (int i = 0; i < 10; i++)
            s += wi[i] * xr[lane + 64 * i] + wh[i] * hr[lane + 64 * i];
#pragma unroll
        for (int off = 32; off > 0; off >>= 1)
            s += __shfl_down(s, off, 64);
        if (lane == 0) gates[(size_t)b * (4 * H_) + n] = s + bias;
    }
}

// ---------------- LSTM pointwise update (+ optional target_length passthrough) ----------------
__global__ void lstm_update_k(const float* __restrict__ gates, const float* __restrict__ c_in,
                              float* __restrict__ h_out, float* __restrict__ c_out,
                              const int* __restrict__ tlen, float* __restrict__ tlen_out) {
    int idx = blockIdx.x * blockDim.x + threadIdx.x;
    if (tlen_out != nullptr && idx < B_) tlen_out[idx] = (float)tlen[idx];
    if (idx >= B_ * H_) return;
    int b = idx / H_, j = idx - b * H_;
    const float* gr = gates + (size_t)b * 4 * H_;
    float ig = 1.f / (1.f + expf(-gr[j]));
    float fg = 1.f / (1.f + expf(-gr[H_ + j]));
    float gg = tanhf(gr[2 * H_ + j]);
    float og = 1.f / (1.f + expf(-gr[3 * H_ + j]));
    float c  = fg * c_in[idx] + ig * gg;
    h_out[idx] = og * tanhf(c);
    c_out[idx] = c;
}

// ---------------- g[b][j] = h1_b . wpred[j] + bpred[j] ----------------
__global__ void pred_g_k(const float* __restrict__ h1, const float* __restrict__ wp,
                         const float* __restrict__ bp, float* __restrict__ g) {
    int j = blockIdx.x, lane = threadIdx.x;
    float w[10];
#pragma unroll
    for (int i = 0; i < 10; i++) w[i] = wp[(size_t)j * H_ + lane + 64 * i];
    for (int b = 0; b < B_; b++) {
        const float* hr = h1 + (size_t)b * H_;
        float s = 0.f;
#pragma unroll
        for (int i = 0; i < 10; i++) s += w[i] * hr[lane + 64 * i];
#pragma unroll
        for (int off = 32; off > 0; off >>= 1)
            s += __shfl_down(s, off, 64);
        if (lane == 0) g[(size_t)b * J_ + j] = s + bp[j];
    }
}

// ---------------- m97-style bf16 MFMA GEMM, C = A (MxK) * B^T (NxK) ----------------
// Used for GEMM1 (N=640 not divisible by 256).
template <int K, int EPI>
__global__ __launch_bounds__(256) void gemm_bt_k(
        const unsigned short* __restrict__ A, const unsigned short* __restrict__ Bm,
        const float* __restrict__ bias, const float* __restrict__ g,
        float* __restrict__ outF, unsigned short* __restrict__ outU, int ldn) {
    __shared__ __align__(16) unsigned short As[128 * 32];
    __shared__ __align__(16) unsigned short Bs[128 * 32];
    const int tid  = threadIdx.x;
    const int w    = tid >> 6;          // wave 0..3
    const int lane = tid & 63;
    const int tile_n = blockIdx.x * 128;
    const int tile_m = blockIdx.y * 128;
    const int wm = w & 1, wn = w >> 1;  // wave -> 64x64 quadrant
    const int l15 = lane & 15, quad = lane >> 4;
    const int lr = lane >> 2, lc = lane & 3;  // staging: row-in-chunk, 16B slot

    f32x4 zero = {0.f, 0.f, 0.f, 0.f};
    f32x4 acc[4][4];
#pragma unroll
    for (int i = 0; i < 4; i++)
#pragma unroll
        for (int j = 0; j < 4; j++) acc[i][j] = zero;

    for (int k0 = 0; k0 < K; k0 += 32) {
#pragma unroll
        for (int cc = 0; cc < 2; cc++) {
            const int c = 2 * w + cc;
            const char* ga = (const char*)(A + (size_t)(tile_m + 16 * c + lr) * K)
                             + (size_t)k0 * 2 + lc * 16;
            __builtin_amdgcn_global_load_lds((const GloV*)ga,
                    (LdsV*)((char*)As + c * 1024), 16, 0, 0);
            const char* gb = (const char*)(Bm + (size_t)(tile_n + 16 * c + lr) * K)
                             + (size_t)k0 * 2 + lc * 16;
            __builtin_amdgcn_global_load_lds((const GloV*)gb,
                    (LdsV*)((char*)Bs + c * 1024), 16, 0, 0);
        }
        __syncthreads();

        bf16x8 av[4], bv[4];
#pragma unroll
        for (int i = 0; i < 4; i++) {
            av[i] = *(const bf16x8*)&As[(wm * 64 + i * 16 + l15) * 32 + quad * 8];
            bv[i] = *(const bf16x8*)&Bs[(wn * 64 + i * 16 + l15) * 32 + quad * 8];
        }
#pragma unroll
        for (int i = 0; i < 4; i++)
#pragma unroll
            for (int j = 0; j < 4; j++)
                acc[i][j] = __builtin_amdgcn_mfma_f32_16x16x32_bf16(av[i], bv[j], acc[i][j], 0, 0, 0);
        __syncthreads();
    }

#pragma unroll
    for (int i = 0; i < 4; i++) {
        const int mb = tile_m + wm * 64 + i * 16 + quad * 4;
#pragma unroll
        for (int j = 0; j < 4; j++) {
            const int n = tile_n + wn * 64 + j * 16 + l15;
#pragma unroll
            for (int r = 0; r < 4; r++) {
                float v = acc[i][j][r] + bias[n];
                if (EPI == 0) {
                    outF[(size_t)(mb + r) * ldn + n] = v;
                } else {
                    v += g[(size_t)((mb + r) >> 9) * J_ + n];
                    outU[(size_t)(mb + r) * ldn + n] = f2bf(fmaxf(v, 0.f));
                }
            }
        }
    }
}

// ---------------- 256x256 deep-pipeline bf16 GEMM, C = A (MxK) * B^T (NxK) + bias ----------------
// 8 waves (2M x 4N), BK=64, 128 KiB STATIC double-buffered LDS (gfx950 has 160 KiB/CU).
// Counted vmcnt(8): the 8 staging loads for tile t+2 stay in flight across the
// barrier; the wait guarantees tile t+1 has landed. Never drains to 0 mid-loop (T4).
// LDS layout: full 8-row XOR swizzle — phys 16B slot s of row r holds logical chunk
// s^(r&7). Applied as inverse-permuted GLOBAL source (global_load_lds dest must stay
// linear: rule #21) + the same XOR on the ds_read address (T2).
template <int M, int N, int K>
__global__ __launch_bounds__(512, 2) void gemm256_k(
        const unsigned short* __restrict__ A, const unsigned short* __restrict__ Bm,
        const float* __restrict__ bias, float* __restrict__ out) {
    __shared__ __align__(16) char lds[131072];   // [0,64K): A dbuf; [64K,128K): B dbuf
    constexpr int NT  = K / 64;
    constexpr int K2  = K * 2;                   // global row stride in bytes
    constexpr int NTN = N / 256;
    constexpr int NWG = (M / 256) * NTN;         // 1024 here (divisible by 8)

    // XCD-aware bijective swizzle: each XCD gets a contiguous chunk of logical tiles (T1)
    const int bid = blockIdx.x;
    const int swz = (bid & 7) * (NWG / 8) + (bid >> 3);
    const int tile_n = (swz % NTN) * 256;
    const int tile_m = (swz / NTN) * 256;

    const int tid  = threadIdx.x;
    const int w    = tid >> 6;                   // wave 0..7
    const int l    = tid & 63;
    const int wm   = w >> 2;                     // 0..1 -> 128-row half
    const int wn   = w & 3;                      // 0..3 -> 64-col slice
    const int l15  = l & 15, quad = l >> 4;

    // staging: per wave 4 x 1KiB blocks per matrix per K-tile (8 rows x 128B each).
    // global_load_lds writes lane l at dest+16*l (linear). Source pre-swizzled:
    // row = blk*8 + (l>>3), logical col-chunk = (l&7) ^ (l>>3).
    const int lrow = l >> 3;
    const int lcc  = (l & 7) ^ lrow;
    const char* gA[4];
    const char* gB[4];
    int blk[4];
#pragma unroll
    for (int q = 0; q < 4; q++) {
        blk[q] = (q >> 1) * 16 + w * 2 + (q & 1);    // 1KiB-block index 0..31 in 32KiB tile
        gA[q] = (const char*)A  + (size_t)(tile_m + blk[q] * 8 + lrow) * K2 + lcc * 16;
        gB[q] = (const char*)Bm + (size_t)(tile_n + blk[q] * 8 + lrow) * K2 + lcc * 16;
    }
    auto stage = [&](int kt) {
        char* la = lds + (kt & 1) * 32768;
        char* lb = lds + 65536 + (kt & 1) * 32768;
        const int kb = kt * 128;
#pragma unroll
        for (int q = 0; q < 4; q++)
            __builtin_amdgcn_global_load_lds((const GloV*)(gA[q] + kb),
                    (LdsV*)(la + blk[q] * 1024), 16, 0, 0);
#pragma unroll
        for (int q = 0; q < 4; q++)
            __builtin_amdgcn_global_load_lds((const GloV*)(gB[q] + kb),
                    (LdsV*)(lb + blk[q] * 1024), 16, 0, 0);
    };

    // read-side swizzled column byte offsets (row&7 == l15&7 for every subtile we read,
    // since all row offsets are multiples of 16)
    const int colk0 = (quad * 16) ^ ((l15 & 7) << 4);   // kstep 0 (k 0..31)
    const int colk1 = colk0 ^ 64;                       // kstep 1 (k 32..63)
    const int arow  = (wm * 128 + l15) * 128;           // byte offset of A frag base row
    const int brow  = (wn * 64 + l15) * 128;            // byte offset of B frag base row

    f32x4 acc[8][4];
    f32x4 zero = {0.f, 0.f, 0.f, 0.f};
#pragma unroll
    for (int i = 0; i < 8; i++)
#pragma unroll
        for (int j = 0; j < 4; j++) acc[i][j] = zero;

    stage(0);
    stage(1);
    asm volatile("s_waitcnt vmcnt(8)" ::: "memory");     // own tile-0 loads landed
    sbar();                                              // cross-wave visibility

    for (int t = 0; t < NT; ++t) {
        const char* la = lds + (t & 1) * 32768;
        const char* lb = lds + 65536 + (t & 1) * 32768;

        bf16x8 bv[2][4];
#pragma unroll
        for (int j = 0; j < 4; j++) {
            bv[0][j] = *(const bf16x8*)(lb + brow + j * 2048 + colk0);
            bv[1][j] = *(const bf16x8*)(lb + brow + j * 2048 + colk1);
        }
        bf16x8 ap[2][2][2];   // [ping][row01][ks] — all indices static after unroll
        ap[0][0][0] = *(const bf16x8*)(la + arow + 0 * 2048 + colk0);
        ap[0][0][1] = *(const bf16x8*)(la + arow + 0 * 2048 + colk1);
        ap[0][1][0] = *(const bf16x8*)(la + arow + 1 * 2048 + colk0);
        ap[0][1][1] = *(const bf16x8*)(la + arow + 1 * 2048 + colk1);

#pragma unroll
        for (int ph = 0; ph < 4; ph++) {
            const int cur = ph & 1, nxt = cur ^ 1;
            if (ph < 3) {   // prefetch next phase's A rows while MFMAs run
                ap[nxt][0][0] = *(const bf16x8*)(la + arow + (2 * ph + 2) * 2048 + colk0);
                ap[nxt][0][1] = *(const bf16x8*)(la + arow + (2 * ph + 2) * 2048 + colk1);
                ap[nxt][1][0] = *(const bf16x8*)(la + arow + (2 * ph + 3) * 2048 + colk0);
                ap[nxt][1][1] = *(const bf16x8*)(la + arow + (2 * ph + 3) * 2048 + colk1);
            }
            __builtin_amdgcn_s_setprio(1);               // T5: favor MFMA cluster
#pragma unroll
            for (int ii = 0; ii < 2; ii++)
#pragma unroll
                for (int j = 0; j < 4; j++) {
                    acc[2 * ph + ii][j] = __builtin_amdgcn_mfma_f32_16x16x32_bf16(
                            ap[cur][ii][0], bv[0][j], acc[2 * ph + ii][j], 0, 0, 0);
                    acc[2 * ph + ii][j] = __builtin_amdgcn_mfma_f32_16x16x32_bf16(
                            ap[cur][ii][1], bv[1][j], acc[2 * ph + ii][j], 0, 0, 0);
                }
            __builtin_amdgcn_s_setprio(0);
        }

        sbar();                              // all waves done READING buf (t&1)
        if (t + 2 < NT) {
            stage(t + 2);                    // overwrite buf (t&1)
            asm volatile("s_waitcnt vmcnt(8)" ::: "memory");  // own tile t+1 loads landed
        } else {
            asm volatile("s_waitcnt vmcnt(0)" ::: "memory");  // tail drain
        }
        sbar();                              // all waves' tile t+1 loads visible
    }

    // epilogue: C/D layout col=lane&15, row=quad*4+reg (m89-verified)
    const int cb = tile_n + wn * 64 + l15;
    float bj[4];
#pragma unroll
    for (int j = 0; j < 4; j++) bj[j] = bias[cb + j * 16];
    const int r0 = tile_m + wm * 128 + quad * 4;
#pragma unroll
    for (int i = 0; i < 8; i++)
#pragma unroll
        for (int r = 0; r < 4; r++) {
            float* orow = out + (size_t)(r0 + i * 16 + r) * N;
#pragma unroll
            for (int j = 0; j < 4; j++)
                orow[cb + j * 16] = acc[i][j][r] + bj[j];
        }
}

extern "C" void kernel_launch(void* const* d_in, const int* in_sizes, int n_in,
                              void* d_out, int out_size, void* d_ws, size_t ws_size,
                              hipStream_t stream) {
    const float* enc   = (const float*)d_in[0];
    const int*   tgt   = (const int*)d_in[1];
    const int*   tlen  = (const int*)d_in[2];
    const float* st1   = (const float*)d_in[3];   // (2,B,H) h states
    const float* st2   = (const float*)d_in[4];   // (2,B,H) c states
    const float* wih0  = (const float*)d_in[5];
    const float* whh0  = (const float*)d_in[6];
    const float* bih0  = (const float*)d_in[7];
    const float* bhh0  = (const float*)d_in[8];
    const float* wih1  = (const float*)d_in[9];
    const float* whh1  = (const float*)d_in[10];
    const float* bih1  = (const float*)d_in[11];
    const float* bhh1  = (const float*)d_in[12];
    const float* emb   = (const float*)d_in[13];
    const float* wenc  = (const float*)d_in[14];
    const float* benc  = (const float*)d_in[15];
    const float* wpred = (const float*)d_in[16];
    const float* bpred = (const float*)d_in[17];
    const float* wout  = (const float*)d_in[18];
    const float* bout  = (const float*)d_in[19];

    float* out      = (float*)d_out;
    float* out_tlen = out + (size_t)B_ * T_ * V_;
    float* h0 = out_tlen + B_;            // output_states_1[0]
    float* h1 = h0 + B_ * H_;             // output_states_1[1]
    float* c0 = h1 + B_ * H_;             // output_states_2[0]
    float* c1 = c0 + B_ * H_;             // output_states_2[1]

    // workspace layout (~44.1 MB)
    unsigned short* encB  = (unsigned short*)d_ws;                 // 16384*512 bf16
    unsigned short* pB    = encB + (size_t)B_ * T_ * DE_;          // 16384*640 bf16
    unsigned short* woutB = pB + (size_t)B_ * T_ * J_;             // 4096*640 bf16
    unsigned short* wencB = woutB + (size_t)V_ * J_;               // 640*512 bf16
    float* gates = (float*)(wencB + (size_t)J_ * DE_);             // 32*2560 f32
    float* gvec  = gates + B_ * 4 * H_;                            // 32*640 f32

    // weight converts + encoder transpose (independent)
    conv_f32_bf16_k<<<(V_ * J_ + 255) / 256, 256, 0, stream>>>(wout, woutB, V_ * J_);
    conv_f32_bf16_k<<<(J_ * DE_ + 255) / 256, 256, 0, stream>>>(wenc, wencB, J_ * DE_);
    enc_transpose_k<<<dim3(T_ / 32, DE_ / 32, B_), 256, 0, stream>>>(enc, encB);

    // LSTM layer 0 (x = embed[targets])
    lstm_gates_k<<<4 * H_, 64, 0, stream>>>(nullptr, tgt, emb, st1, wih0, whh0, bih0, bhh0, gates);
    lstm_update_k<<<(B_ * H_ + 255) / 256, 256, 0, stream>>>(gates, st2, h0, c0, tlen, out_tlen);
    // LSTM layer 1 (x = h0)
    lstm_gates_k<<<4 * H_, 64, 0, stream>>>(h0, nullptr, nullptr, st1 + B_ * H_, wih1, whh1, bih1, bhh1, gates);
    lstm_update_k<<<(B_ * H_ + 255) / 256, 256, 0, stream>>>(gates, st2 + B_ * H_, h1, c1, nullptr, nullptr);
    // g = h1 @ W_pred^T + b_pred
    pred_g_k<<<J_, 64, 0, stream>>>(h1, wpred, bpred, gvec);

    // P = bf16(relu(enc @ W_enc^T + b_enc + g))   [M=16384, N=640, K=512]
    gemm_bt_k<DE_, 1><<<dim3(J_ / 128, (B_ * T_) / 128), 256, 0, stream>>>(
        encB, wencB, benc, gvec, nullptr, pB, J_);

    // out = P @ W_out^T + b_out                   [M=16384, N=4096, K=640]
    // 256^2 deep-pipeline kernel, 128 KiB static LDS (no dynamic-LDS attribute needed).
    gemm256_k<B_ * T_, V_, J_><<<dim3((B_ * T_ / 256) * (V_ / 256)), 512, 0, stream>>>(
        pB, woutB, bout, out);
}

// Round 3
// 517.327 us; speedup vs baseline: 1.0370x; 1.0282x over previous
//
#include <hip/hip_runtime.h>
#include <stdint.h>

// Problem dims
#define B_  32
#define T_  512
#define DE_ 512
#define H_  640
#define V_  4096
#define J_  640

typedef __attribute__((ext_vector_type(4))) float  f32x4;
typedef __attribute__((ext_vector_type(8))) __bf16 bf16x8;

typedef __attribute__((address_space(3))) void LdsV;
typedef __attribute__((address_space(1))) void GloV;

__device__ __forceinline__ unsigned short f2bf(float f) {
    uint32_t u = __builtin_bit_cast(uint32_t, f);
    u += 0x7fffu + ((u >> 16) & 1u);   // round-to-nearest-even
    return (unsigned short)(u >> 16);
}

// raw barrier with compiler fence (no implicit vmcnt(0) drain, unlike __syncthreads)
__device__ __forceinline__ void sbar() { asm volatile("s_barrier" ::: "memory"); }

// ---------------- fp32 -> bf16 elementwise convert ----------------
__global__ void conv_f32_bf16_k(const float* __restrict__ src,
                                unsigned short* __restrict__ dst, int n) {
    int i = blockIdx.x * blockDim.x + threadIdx.x;
    if (i < n) dst[i] = f2bf(src[i]);
}

// ---------------- encoder (B,D,T) -> bf16 (B*T, D) transpose ----------------
__global__ void enc_transpose_k(const float* __restrict__ enc,
                                unsigned short* __restrict__ out) {
    __shared__ float tile[32][33];
    int b  = blockIdx.z;
    int t0 = blockIdx.x * 32, d0 = blockIdx.y * 32;
    int tx = threadIdx.x & 31;
    int ty = (threadIdx.x >> 5) * 4;
    const float* src = enc + ((size_t)b * DE_ + d0) * T_ + t0;
#pragma unroll
    for (int i = 0; i < 4; i++)
        tile[ty + i][tx] = src[(size_t)(ty + i) * T_ + tx];  // coalesced over t
    __syncthreads();
    unsigned short* dst = out + ((size_t)b * T_ + t0) * DE_ + d0;
#pragma unroll
    for (int i = 0; i < 4; i++)
        dst[(size_t)(ty + i) * DE_ + tx] = f2bf(tile[tx][ty + i]);  // coalesced over d
}

// ---------------- LSTM gates: gates[b][n] = x_b . wih[n] + h_b . whh[n] + biases ----------------
__global__ void lstm_gates_k(const float* __restrict__ x, const int* __restrict__ tok,
                             const float* __restrict__ emb, const float* __restrict__ h,
                             const float* __restrict__ wih, const float* __restrict__ whh,
                             const float* __restrict__ bih, const float* __restrict__ bhh,
                             float* __restrict__ gates) {
    int n = blockIdx.x, lane = threadIdx.x;
    float wi[10], wh[10];
#pragma unroll
    for (int i = 0; i < 10; i++) {
        wi[i] = wih[(size_t)n * H_ + lane + 64 * i];   // coalesced
        wh[i] = whh[(size_t)n * H_ + lane + 64 * i];
    }
    float bias = bih[n] + bhh[n];
    for (int b = 0; b < B_; b++) {
        const float* xr = tok ? (emb + (size_t)tok[b] * H_) : (x + (size_t)b * H_);
        const float* hr = h + (size_t)b * H_;
        float s = 0.f;
#pragma unroll
        for (int i = 0; i < 10; i++)
            s += wi[i] * xr[lane + 64 * i] + wh[i] * hr[lane + 64 * i];
#pragma unroll
        for (int off = 32; off > 0; off >>= 1)
            s += __shfl_down(s, off, 64);
        if (lane == 0) gates[(size_t)b * (4 * H_) + n] = s + bias;
    }
}

// ---------------- LSTM pointwise update (+ optional target_length passthrough) ----------------
__global__ void lstm_update_k(const float* __restrict__ gates, const float* __restrict__ c_in,
                              float* __restrict__ h_out, float* __restrict__ c_out,
                              const int* __restrict__ tlen, float* __restrict__ tlen_out) {
    int idx = blockIdx.x * blockDim.x + threadIdx.x;
    if (tlen_out != nullptr && idx < B_) tlen_out[idx] = (float)tlen[idx];
    if (idx >= B_ * H_) return;
    int b = idx / H_, j = idx - b * H_;
    const float* gr = gates + (size_t)b * 4 * H_;
    float ig = 1.f / (1.f + expf(-gr[j]));
    float fg = 1.f / (1.f + expf(-gr[H_ + j]));
    float gg = tanhf(gr[2 * H_ + j]);
    float og = 1.f / (1.f + expf(-gr[3 * H_ + j]));
    float c  = fg * c_in[idx] + ig * gg;
    h_out[idx] = og * tanhf(c);
    c_out[idx] = c;
}

// ---------------- g[b][j] = h1_b . wpred[j] + bpred[j] ----------------
__global__ void pred_g_k(const float* __restrict__ h1, const float* __restrict__ wp,
                         const float* __restrict__ bp, float* __restrict__ g) {
    int j = blockIdx.x, lane = threadIdx.x;
    float w[10];
#pragma unroll
    for (int i = 0; i < 10; i++) w[i] = wp[(size_t)j * H_ + lane + 64 * i];
    for (int b = 0; b < B_; b++) {
        const float* hr = h1 + (size_t)b * H_;
        float s = 0.f;
#pragma unroll
        for (int i = 0; i < 10; i++) s += w[i] * hr[lane + 64 * i];
#pragma unroll
        for (int off = 32; off > 0; off >>= 1)
            s += __shfl_down(s, off, 64);
        if (lane == 0) g[(size_t)b * J_ + j] = s + bp[j];
    }
}

// ---------------- m97-style bf16 MFMA GEMM, C = A (MxK) * B^T (NxK) ----------------
// Used for GEMM1 (N=640 not divisible by 256).
template <int K, int EPI>
__global__ __launch_bounds__(256) void gemm_bt_k(
        const unsigned short* __restrict__ A, const unsigned short* __restrict__ Bm,
        const float* __restrict__ bias, const float* __restrict__ g,
        float* __restrict__ outF, unsigned short* __restrict__ outU, int ldn) {
    __shared__ __align__(16) unsigned short As[128 * 32];
    __shared__ __align__(16) unsigned short Bs[128 * 32];
    const int tid  = threadIdx.x;
    const int w    = tid >> 6;          // wave 0..3
    const int lane = tid & 63;
    const int tile_n = blockIdx.x * 128;
    const int tile_m = blockIdx.y * 128;
    const int wm = w & 1, wn = w >> 1;  // wave -> 64x64 quadrant
    const int l15 = lane & 15, quad = lane >> 4;
    const int lr = lane >> 2, lc = lane & 3;  // staging: row-in-chunk, 16B slot

    f32x4 zero = {0.f, 0.f, 0.f, 0.f};
    f32x4 acc[4][4];
#pragma unroll
    for (int i = 0; i < 4; i++)
#pragma unroll
        for (int j = 0; j < 4; j++) acc[i][j] = zero;

    for (int k0 = 0; k0 < K; k0 += 32) {
#pragma unroll
        for (int cc = 0; cc < 2; cc++) {
            const int c = 2 * w + cc;
            const char* ga = (const char*)(A + (size_t)(tile_m + 16 * c + lr) * K)
                             + (size_t)k0 * 2 + lc * 16;
            __builtin_amdgcn_global_load_lds((const GloV*)ga,
                    (LdsV*)((char*)As + c * 1024), 16, 0, 0);
            const char* gb = (const char*)(Bm + (size_t)(tile_n + 16 * c + lr) * K)
                             + (size_t)k0 * 2 + lc * 16;
            __builtin_amdgcn_global_load_lds((const GloV*)gb,
                    (LdsV*)((char*)Bs + c * 1024), 16, 0, 0);
        }
        __syncthreads();

        bf16x8 av[4], bv[4];
#pragma unroll
        for (int i = 0; i < 4; i++) {
            av[i] = *(const bf16x8*)&As[(wm * 64 + i * 16 + l15) * 32 + quad * 8];
            bv[i] = *(const bf16x8*)&Bs[(wn * 64 + i * 16 + l15) * 32 + quad * 8];
        }
#pragma unroll
        for (int i = 0; i < 4; i++)
#pragma unroll
            for (int j = 0; j < 4; j++)
                acc[i][j] = __builtin_amdgcn_mfma_f32_16x16x32_bf16(av[i], bv[j], acc[i][j], 0, 0, 0);
        __syncthreads();
    }

#pragma unroll
    for (int i = 0; i < 4; i++) {
        const int mb = tile_m + wm * 64 + i * 16 + quad * 4;
#pragma unroll
        for (int j = 0; j < 4; j++) {
            const int n = tile_n + wn * 64 + j * 16 + l15;
#pragma unroll
            for (int r = 0; r < 4; r++) {
                float v = acc[i][j][r] + bias[n];
                if (EPI == 0) {
                    outF[(size_t)(mb + r) * ldn + n] = v;
                } else {
                    v += g[(size_t)((mb + r) >> 9) * J_ + n];
                    outU[(size_t)(mb + r) * ldn + n] = f2bf(fmaxf(v, 0.f));
                }
            }
        }
    }
}

// ---------------- 256x256 8-phase deep-pipeline bf16 GEMM (T1+T2+T3+T4+T5) ----------------
// C = A (MxK) * B^T (NxK) + bias.  8 waves (2M x 4N), BK=64, 128 KiB static dbuf LDS.
// Per K-tile t: 4 phases, each = {ds_read subtile || stage 1 half-tile (2 loads/thread)
//   -> s_barrier -> lgkmcnt(0) -> setprio(1) -> 16 MFMA -> setprio(0) -> s_barrier}.
// B fragments for the whole K-tile are register-loaded in phase 0 (closes B-region reads
// so B halves can be overwritten from p1 on); A halves are wave-pinned so A(t+1) halves
// stage at t:p0/p1 into the OTHER buffer.  Staging: p0:A0(t+1) p1:A1(t+1) p2:B0(t+2)
// p3:B1(t+2).  One counted vmcnt(4) per K-tile (after p3 MFMAs): exactly the 2 halves
// issued after tile t+1's last half stay in flight -- never drains to 0 mid-loop (T4).
// LDS XOR swizzle (T2): phys 16B slot s of row r holds logical slot s^(r&7); applied as
// inverse-permuted global source (global_load_lds dest stays linear, rule #21) + same
// XOR on ds_read addresses.
template <int M, int N, int K>
__global__ __launch_bounds__(512, 2) void gemm256_k(
        const unsigned short* __restrict__ A, const unsigned short* __restrict__ Bm,
        const float* __restrict__ bias, float* __restrict__ out) {
    __shared__ __align__(16) char lds[131072];   // A: [0,64K) dbuf; B: [64K,128K) dbuf
    constexpr int NT  = K / 64;
    constexpr int K2  = K * 2;                   // global row stride in bytes
    constexpr int NTN = N / 256;
    constexpr int NWG = (M / 256) * NTN;         // 1024 here (divisible by 8)

    // T1: XCD-aware bijective swizzle (NWG % 8 == 0)
    const int bid = blockIdx.x;
    const int swz = (bid & 7) * (NWG / 8) + (bid >> 3);
    const int tile_n = (swz % NTN) * 256;
    const int tile_m = (swz / NTN) * 256;

    const int tid  = threadIdx.x;
    const int w    = tid >> 6;                   // wave 0..7
    const int l    = tid & 63;
    const int wm   = w >> 2;                     // 0..1 -> 128-row half of C-tile
    const int wn   = w & 3;                      // 0..3 -> 64-col slice
    const int l15  = l & 15, quad = l >> 4;

    // staging geometry: half-tile = 128 rows x 128 B = 16 KiB = 16 blocks of (8 rows x 128 B).
    // wave w covers blocks 2w, 2w+1.  global_load_lds writes lane l at dest + 16*l (linear):
    // byte (l>>3)*128 + (l&7)*16 -> row lrow, phys slot l&7.  Source pre-swizzled:
    // logical col chunk lcc = (l&7) ^ lrow  (involution with read-side XOR).
    const int lrow = l >> 3;
    const int lcc  = (l & 7) ^ lrow;
    const char* gAb = (const char*)A  + (size_t)tile_m * K2;
    const char* gBb = (const char*)Bm + (size_t)tile_n * K2;

    auto stageA = [&](int h, int kt) {   // half h of A K-tile kt -> buf (kt&1)
        char* d = lds + (kt & 1) * 32768 + h * 16384 + w * 2048;
        const char* s = gAb + (size_t)(h * 128 + w * 16 + lrow) * K2 + kt * 128 + lcc * 16;
        __builtin_amdgcn_global_load_lds((const GloV*)s, (LdsV*)d, 16, 0, 0);
        __builtin_amdgcn_global_load_lds((const GloV*)(s + (size_t)8 * K2),
                                         (LdsV*)(d + 1024), 16, 0, 0);
    };
    auto stageB = [&](int h, int kt) {
        char* d = lds + 65536 + (kt & 1) * 32768 + h * 16384 + w * 2048;
        const char* s = gBb + (size_t)(h * 128 + w * 16 + lrow) * K2 + kt * 128 + lcc * 16;
        __builtin_amdgcn_global_load_lds((const GloV*)s, (LdsV*)d, 16, 0, 0);
        __builtin_amdgcn_global_load_lds((const GloV*)(s + (size_t)8 * K2),
                                         (LdsV*)(d + 1024), 16, 0, 0);
    };

    // read-side swizzled offsets.  rows read are (16-multiple + l15) => row&7 == l15&7.
    const int colk0 = (quad * 16) ^ ((l15 & 7) << 4);   // kstep 0 (k 0..31)
    const int colk1 = colk0 ^ 64;                       // kstep 1 (k 32..63)
    const int arow  = wm * 16384 + l15 * 128;           // A frag base byte (within buf)
    const int brow  = wn * 8192 + l15 * 128;            // B frag base byte (within buf)

    f32x4 acc[8][4];
    f32x4 zero = {0.f, 0.f, 0.f, 0.f};
#pragma unroll
    for (int i = 0; i < 8; i++)
#pragma unroll
        for (int j = 0; j < 4; j++) acc[i][j] = zero;

    // prologue: tile 0 fully + B halves of tile 1 (per steady-state schedule).
    stageA(0, 0); stageA(1, 0); stageB(0, 0); stageB(1, 0);
    stageB(0, 1); stageB(1, 1);
    asm volatile("s_waitcnt vmcnt(4)" ::: "memory");   // tile 0's 8 loads landed
    sbar();

    for (int t = 0; t < NT; ++t) {
        const char* la = lds + (t & 1) * 32768;
        const char* lb = lds + 65536 + (t & 1) * 32768;

        bf16x8 bv0[4], bv1[4];
#pragma unroll
        for (int p = 0; p < 4; p++) {
            bf16x8 av[2][2];
            if (p == 0) {   // whole-K-tile B fragments -> regs (closes B-region reads)
#pragma unroll
                for (int j = 0; j < 4; j++) {
                    bv0[j] = *(const bf16x8*)(lb + brow + j * 2048 + colk0);
                    bv1[j] = *(const bf16x8*)(lb + brow + j * 2048 + colk1);
                }
            }
            av[0][0] = *(const bf16x8*)(la + arow + (2 * p) * 2048 + colk0);
            av[0][1] = *(const bf16x8*)(la + arow + (2 * p) * 2048 + colk1);
            av[1][0] = *(const bf16x8*)(la + arow + (2 * p + 1) * 2048 + colk0);
            av[1][1] = *(const bf16x8*)(la + arow + (2 * p + 1) * 2048 + colk1);

            // staging schedule (write-after-read safe; see header comment)
            if (p == 0) {
                if (t + 1 < NT) stageA(0, t + 1);
                asm volatile("s_waitcnt lgkmcnt(8)" ::: "memory");  // 12 reads this phase
            } else if (p == 1) {
                if (t + 1 < NT) stageA(1, t + 1);
            } else if (p == 2) {
                if (t + 2 < NT) stageB(0, t + 2);
            } else {
                if (t + 2 < NT) stageB(1, t + 2);
            }

            sbar();
            asm volatile("s_waitcnt lgkmcnt(0)" ::: "memory");
            __builtin_amdgcn_s_setprio(1);
#pragma unroll
            for (int ii = 0; ii < 2; ii++)
#pragma unroll
                for (int j = 0; j < 4; j++) {
                    acc[2 * p + ii][j] = __builtin_amdgcn_mfma_f32_16x16x32_bf16(
                            av[ii][0], bv0[j], acc[2 * p + ii][j], 0, 0, 0);
                    acc[2 * p + ii][j] = __builtin_amdgcn_mfma_f32_16x16x32_bf16(
                            av[ii][1], bv1[j], acc[2 * p + ii][j], 0, 0, 0);
                }
            __builtin_amdgcn_s_setprio(0);

            if (p == 3) {   // T4: counted wait -- tile t+1 landed, newest 2 halves in flight
                if (t + 2 < NT) asm volatile("s_waitcnt vmcnt(4)" ::: "memory");
                else           asm volatile("s_waitcnt vmcnt(0)" ::: "memory");
            }
            sbar();
        }
    }

    // epilogue: C/D layout col=lane&15, row=quad*4+reg (m89-verified)
    const int cb = tile_n + wn * 64 + l15;
    float bj[4];
#pragma unroll
    for (int j = 0; j < 4; j++) bj[j] = bias[cb + j * 16];
    const int r0 = tile_m + wm * 128 + quad * 4;
#pragma unroll
    for (int i = 0; i < 8; i++)
#pragma unroll
        for (int r = 0; r < 4; r++) {
            float* orow = out + (size_t)(r0 + i * 16 + r) * N;
#pragma unroll
            for (int j = 0; j < 4; j++)
                orow[cb + j * 16] = acc[i][j][r] + bj[j];
        }
}

extern "C" void kernel_launch(void* const* d_in, const int* in_sizes, int n_in,
                              void* d_out, int out_size, void* d_ws, size_t ws_size,
                              hipStream_t stream) {
    const float* enc   = (const float*)d_in[0];
    const int*   tgt   = (const int*)d_in[1];
    const int*   tlen  = (const int*)d_in[2];
    const float* st1   = (const float*)d_in[3];   // (2,B,H) h states
    const float* st2   = (const float*)d_in[4];   // (2,B,H) c states
    const float* wih0  = (const float*)d_in[5];
    const float* whh0  = (const float*)d_in[6];
    const float* bih0  = (const float*)d_in[7];
    const float* bhh0  = (const float*)d_in[8];
    const float* wih1  = (const float*)d_in[9];
    const float* whh1  = (const float*)d_in[10];
    const float* bih1  = (const float*)d_in[11];
    const float* bhh1  = (const float*)d_in[12];
    const float* emb   = (const float*)d_in[13];
    const float* wenc  = (const float*)d_in[14];
    const float* benc  = (const float*)d_in[15];
    const float* wpred = (const float*)d_in[16];
    const float* bpred = (const float*)d_in[17];
    const float* wout  = (const float*)d_in[18];
    const float* bout  = (const float*)d_in[19];

    float* out      = (float*)d_out;
    float* out_tlen = out + (size_t)B_ * T_ * V_;
    float* h0 = out_tlen + B_;            // output_states_1[0]
    float* h1 = h0 + B_ * H_;             // output_states_1[1]
    float* c0 = h1 + B_ * H_;             // output_states_2[0]
    float* c1 = c0 + B_ * H_;             // output_states_2[1]

    // workspace layout (~44.1 MB)
    unsigned short* encB  = (unsigned short*)d_ws;                 // 16384*512 bf16
    unsigned short* pB    = encB + (size_t)B_ * T_ * DE_;          // 16384*640 bf16
    unsigned short* woutB = pB + (size_t)B_ * T_ * J_;             // 4096*640 bf16
    unsigned short* wencB = woutB + (size_t)V_ * J_;               // 640*512 bf16
    float* gates = (float*)(wencB + (size_t)J_ * DE_);             // 32*2560 f32
    float* gvec  = gates + B_ * 4 * H_;                            // 32*640 f32

    // weight converts + encoder transpose (independent)
    conv_f32_bf16_k<<<(V_ * J_ + 255) / 256, 256, 0, stream>>>(wout, woutB, V_ * J_);
    conv_f32_bf16_k<<<(J_ * DE_ + 255) / 256, 256, 0, stream>>>(wenc, wencB, J_ * DE_);
    enc_transpose_k<<<dim3(T_ / 32, DE_ / 32, B_), 256, 0, stream>>>(enc, encB);

    // LSTM layer 0 (x = embed[targets])
    lstm_gates_k<<<4 * H_, 64, 0, stream>>>(nullptr, tgt, emb, st1, wih0, whh0, bih0, bhh0, gates);
    lstm_update_k<<<(B_ * H_ + 255) / 256, 256, 0, stream>>>(gates, st2, h0, c0, tlen, out_tlen);
    // LSTM layer 1 (x = h0)
    lstm_gates_k<<<4 * H_, 64, 0, stream>>>(h0, nullptr, nullptr, st1 + B_ * H_, wih1, whh1, bih1, bhh1, gates);
    lstm_update_k<<<(B_ * H_ + 255) / 256, 256, 0, stream>>>(gates, st2 + B_ * H_, h1, c1, nullptr, nullptr);
    // g = h1 @ W_pred^T + b_pred
    pred_g_k<<<J_, 64, 0, stream>>>(h1, wpred, bpred, gvec);

    // P = bf16(relu(enc @ W_enc^T + b_enc + g))   [M=16384, N=640, K=512]
    gemm_bt_k<DE_, 1><<<dim3(J_ / 128, (B_ * T_) / 128), 256, 0, stream>>>(
        encB, wencB, benc, gvec, nullptr, pB, J_);

    // out = P @ W_out^T + b_out                   [M=16384, N=4096, K=640]
    gemm256_k<B_ * T_, V_, J_><<<dim3((B_ * T_ / 256) * (V_ / 256)), 512, 0, stream>>>(
        pB, woutB, bout, out);
}